// Round 2
// baseline (7133.295 us; speedup 1.0000x reference)
//
#include <hip/hip_runtime.h>
#include <math.h>

#define BB 4
#define NN 2048
#define EE 16384
#define LL (EE + NN)      // 18432
#define MM (BB * LL)      // 73728
#define ND_ 256
#define ED_ 128
#define TD_ 64
#define CC 512
#define HH 8
#define DH_ 64
#define C4 2048

enum { SRC_PLAIN = 0, SRC_NODE = 1, SRC_TIME = 2, SRC_EDGE = 3 };

struct GatherArgs {
    const float* x;      // (B,N,ND)
    const float* ts;     // (B,N)
    const float* wtemb;  // (TD)
    const float* btemb;  // (TD)
    const float* eattr;  // (B,E,ED)
    const int*   ei;     // (B,2,E)
};

__device__ __forceinline__ float gelu_exact(float v) {
    return 0.5f * v * (1.0f + erff(v * 0.7071067811865475f));
}

// ---------------------------------------------------------------------------
// Generic f32 tiled GEMM: Y[rows x Nout] = A[rows x K] @ W[Nout x K]^T + bias
// A can be a "virtual" gathered matrix (node concat / time encoding / edge).
// Chunked row space: local row r = b*Ec + el, global edge = e0 + el.
// BM=BN=64, BK=16, 256 threads, 4x4 micro-tile per thread.
// ---------------------------------------------------------------------------
template<int SRC, bool GELU>
__global__ __launch_bounds__(256)
void gemm_kernel(const float* __restrict__ A, const float* __restrict__ W,
                 const float* __restrict__ bias, float* __restrict__ Y,
                 int K, int Nout, int e0, int Ec, GatherArgs ga)
{
    __shared__ float As[16][68];   // [k][m]
    __shared__ float Ws[16][68];   // [k][n]

    const int tid  = threadIdx.x;
    const int m0   = blockIdx.y * 64;
    const int n0   = blockIdx.x * 64;
    const int lrow = tid >> 2;          // 0..63
    const int lk4  = (tid & 3) << 2;    // 0,4,8,12
    const int tx   = tid & 15;
    const int ty   = tid >> 4;

    const int grow = m0 + lrow;         // local chunk row
    int gb = 0, ge = 0, isrc = 0, itgt = 0;
    float tsi = 0.f, tsj = 0.f;
    if constexpr (SRC != SRC_PLAIN) {
        gb = grow / Ec;                 // batch
        const int el = grow - gb * Ec;  // local edge
        ge = e0 + el;                   // global edge in [0, LL)
        if (ge < EE) {
            isrc = ga.ei[(gb * 2 + 0) * EE + ge];
            itgt = ga.ei[(gb * 2 + 1) * EE + ge];
        } else {
            isrc = ge - EE;
            itgt = ge - EE;
        }
        if constexpr (SRC == SRC_TIME) {
            tsi = ga.ts[gb * NN + isrc];
            tsj = ga.ts[gb * NN + itgt];
        }
    }
    const float* wrowp = W + (size_t)(n0 + lrow) * K;

    float acc[4][4] = {};

    for (int k0 = 0; k0 < K; k0 += 16) {
        const int kk = k0 + lk4;
        float4 av;
        if constexpr (SRC == SRC_PLAIN) {
            av = *(const float4*)(A + (size_t)grow * K + kk);
        } else if constexpr (SRC == SRC_NODE) {
            if (kk < ND_) av = *(const float4*)(ga.x + ((size_t)gb * NN + isrc) * ND_ + kk);
            else          av = *(const float4*)(ga.x + ((size_t)gb * NN + itgt) * ND_ + (kk - ND_));
        } else if constexpr (SRC == SRC_TIME) {
            const float tt = (kk < TD_) ? tsi : tsj;
            const int   kb = (kk < TD_) ? kk : kk - TD_;
            av.x = sinf(tt * ga.wtemb[kb + 0] + ga.btemb[kb + 0]);
            av.y = sinf(tt * ga.wtemb[kb + 1] + ga.btemb[kb + 1]);
            av.z = sinf(tt * ga.wtemb[kb + 2] + ga.btemb[kb + 2]);
            av.w = sinf(tt * ga.wtemb[kb + 3] + ga.btemb[kb + 3]);
        } else { // SRC_EDGE
            if (ge < EE) av = *(const float4*)(ga.eattr + ((size_t)gb * EE + ge) * ED_ + kk);
            else         av = make_float4(0.f, 0.f, 0.f, 0.f);
        }
        const float4 wv = *(const float4*)(wrowp + kk);

        As[lk4 + 0][lrow] = av.x; As[lk4 + 1][lrow] = av.y;
        As[lk4 + 2][lrow] = av.z; As[lk4 + 3][lrow] = av.w;
        Ws[lk4 + 0][lrow] = wv.x; Ws[lk4 + 1][lrow] = wv.y;
        Ws[lk4 + 2][lrow] = wv.z; Ws[lk4 + 3][lrow] = wv.w;
        __syncthreads();

        #pragma unroll
        for (int k = 0; k < 16; k++) {
            const float4 a4 = *(const float4*)&As[k][ty * 4];
            const float4 w4 = *(const float4*)&Ws[k][tx * 4];
            const float aa[4] = {a4.x, a4.y, a4.z, a4.w};
            const float ww[4] = {w4.x, w4.y, w4.z, w4.w};
            #pragma unroll
            for (int i = 0; i < 4; i++)
                #pragma unroll
                for (int j = 0; j < 4; j++)
                    acc[i][j] += aa[i] * ww[j];
        }
        __syncthreads();
    }

    const int gn = n0 + tx * 4;
    const float4 bi = *(const float4*)(bias + gn);
    const float bb_[4] = {bi.x, bi.y, bi.z, bi.w};
    #pragma unroll
    for (int i = 0; i < 4; i++) {
        float4 ov;
        float o[4];
        #pragma unroll
        for (int j = 0; j < 4; j++) {
            float v = acc[i][j] + bb_[j];
            if constexpr (GELU) v = gelu_exact(v);
            o[j] = v;
        }
        ov.x = o[0]; ov.y = o[1]; ov.z = o[2]; ov.w = o[3];
        *(float4*)(Y + (size_t)(m0 + ty * 4 + i) * Nout + gn) = ov;
    }
}

// ---------------------------------------------------------------------------
// Weight folding:  Wout[c][k] = sum_j Wa[c][j] * Wb[j][k]
// ---------------------------------------------------------------------------
__global__ __launch_bounds__(256)
void comb_w(const float* __restrict__ Wa, const float* __restrict__ Wb,
            float* __restrict__ Wout, int K)
{
    const int idx  = blockIdx.x * 256 + threadIdx.x;
    const int c    = idx / K;
    const int kcol = idx - c * K;
    float acc = 0.f;
    for (int j = 0; j < CC; j++)
        acc += Wa[c * CC + j] * Wb[j * K + kcol];
    Wout[idx] = acc;
}

__global__ __launch_bounds__(256)
void comb_b(const float* __restrict__ Wa, const float* __restrict__ bin,
            const float* __restrict__ ba, float* __restrict__ bout)
{
    const int c = blockIdx.x * 256 + threadIdx.x;
    float acc = ba[c];
    for (int j = 0; j < CC; j++)
        acc += Wa[c * CC + j] * bin[j];
    bout[c] = acc;
}

// ---------------------------------------------------------------------------
// Attention over the batch axis: per (edge, head), 4x4 score matrix.
// One block per local edge, 512 threads = 8 waves; wave h = head h, lane = d.
// Writes ctx in-place over q (block touches only its own edge's rows).
// ---------------------------------------------------------------------------
__global__ __launch_bounds__(512)
void attn_kernel(float* __restrict__ q, const float* __restrict__ k,
                 const float* __restrict__ v, int Ec)
{
    const int e = blockIdx.x;           // local edge
    const int t = threadIdx.x;
    const int h = t >> 6;
    const int d = t & 63;
    const size_t off = (size_t)h * DH_ + d;

    float qv[4], kv[4], vv[4];
    #pragma unroll
    for (int l = 0; l < 4; l++) {
        const size_t r = ((size_t)(l * Ec + e)) * CC + off;
        qv[l] = q[r]; kv[l] = k[r]; vv[l] = v[r];
    }

    float sc[4][4];
    #pragma unroll
    for (int l = 0; l < 4; l++) {
        #pragma unroll
        for (int m = 0; m < 4; m++) {
            float p = qv[l] * kv[m];
            #pragma unroll
            for (int o = 32; o; o >>= 1) p += __shfl_xor(p, o, 64);
            sc[l][m] = p * 0.125f;   // 1/sqrt(DH)
        }
    }

    #pragma unroll
    for (int l = 0; l < 4; l++) {
        const float mx = fmaxf(fmaxf(sc[l][0], sc[l][1]), fmaxf(sc[l][2], sc[l][3]));
        float a[4], s = 0.f;
        #pragma unroll
        for (int m = 0; m < 4; m++) { a[m] = expf(sc[l][m] - mx); s += a[m]; }
        const float inv = 1.0f / s;
        float c = 0.f;
        #pragma unroll
        for (int m = 0; m < 4; m++) c += a[m] * inv * vv[m];
        q[((size_t)(l * Ec + e)) * CC + off] = c;
    }
}

// ---------------------------------------------------------------------------
// out[orow] = LayerNorm(A[r] + Bv[r]) * g + be     (C = 512, 256 threads)
// MAP=false: orow = r (local). MAP=true: orow = b*LL + e0 + el (global d_out).
// ---------------------------------------------------------------------------
template<bool MAP>
__global__ __launch_bounds__(256)
void ln_add_kernel(const float* __restrict__ A, const float* __restrict__ Bv,
                   const float* __restrict__ g, const float* __restrict__ be,
                   float* __restrict__ out, int e0, int Ec)
{
    const int r = blockIdx.x;
    const size_t base = (size_t)r * CC;
    const int t = threadIdx.x;

    const float v0 = A[base + t]       + Bv[base + t];
    const float v1 = A[base + t + 256] + Bv[base + t + 256];

    __shared__ float red[4];
    float s = v0 + v1;
    #pragma unroll
    for (int o = 32; o; o >>= 1) s += __shfl_xor(s, o, 64);
    const int wid = t >> 6, lane = t & 63;
    if (lane == 0) red[wid] = s;
    __syncthreads();
    const float mean = (red[0] + red[1] + red[2] + red[3]) * (1.0f / 512.0f);

    const float d0 = v0 - mean, d1 = v1 - mean;
    float vs = d0 * d0 + d1 * d1;
    #pragma unroll
    for (int o = 32; o; o >>= 1) vs += __shfl_xor(vs, o, 64);
    __syncthreads();
    if (lane == 0) red[wid] = vs;
    __syncthreads();
    const float var = (red[0] + red[1] + red[2] + red[3]) * (1.0f / 512.0f);
    const float rstd = rsqrtf(var + 1e-5f);

    size_t obase;
    if constexpr (MAP) {
        const int b  = r / Ec;
        const int el = r - b * Ec;
        obase = ((size_t)b * LL + e0 + el) * CC;
    } else {
        obase = base;
    }
    out[obase + t]       = d0 * rstd * g[t]       + be[t];
    out[obase + t + 256] = d1 * rstd * g[t + 256] + be[t + 256];
}

// ---------------------------------------------------------------------------
extern "C" void kernel_launch(void* const* d_in, const int* in_sizes, int n_in,
                              void* d_out, int out_size, void* d_ws, size_t ws_size,
                              hipStream_t stream)
{
    const float* x       = (const float*)d_in[0];
    const float* eattr   = (const float*)d_in[1];
    const float* ts      = (const float*)d_in[2];
    const float* W_node  = (const float*)d_in[3];
    const float* b_node  = (const float*)d_in[4];
    const float* W_temb  = (const float*)d_in[5];
    const float* b_temb  = (const float*)d_in[6];
    const float* W_timef = (const float*)d_in[7];
    const float* b_timef = (const float*)d_in[8];
    const float* W_edge  = (const float*)d_in[9];
    const float* b_edge  = (const float*)d_in[10];
    const float* Wq      = (const float*)d_in[11];
    const float* bq      = (const float*)d_in[12];
    const float* Wk      = (const float*)d_in[13];
    const float* bk      = (const float*)d_in[14];
    const float* Wv      = (const float*)d_in[15];
    const float* bv      = (const float*)d_in[16];
    const float* Wo      = (const float*)d_in[17];
    const float* bo      = (const float*)d_in[18];
    const float* W1      = (const float*)d_in[19];
    const float* b1      = (const float*)d_in[20];
    const float* W2      = (const float*)d_in[21];
    const float* b2      = (const float*)d_in[22];
    const float* g1      = (const float*)d_in[23];
    const float* be1     = (const float*)d_in[24];
    const float* g2      = (const float*)d_in[25];
    const float* be2     = (const float*)d_in[26];
    const int*   ei      = (const int*)d_in[27];

    float* out = (float*)d_out;
    float* ws  = (float*)d_ws;

    // Folded weights at the front of ws
    float* W_nq = ws;                    // 512*512
    float* W_tk = W_nq + 262144;         // 512*128
    float* W_ev = W_tk + 65536;          // 512*128
    float* b_nq = W_ev + 65536;          // 512
    float* b_tk = b_nq + 512;
    float* b_ev = b_tk + 512;
    float* cbase = b_ev + 512;           // chunk buffers start here
    const size_t wfloats = 262144 + 65536 + 65536 + 3 * 512;   // 394752

    // Chunk sizing: per edge = 4 rows x (4*512 + 2048) floats = 16384 floats
    const size_t wsf = ws_size / sizeof(float);
    size_t avail = (wsf > wfloats) ? (wsf - wfloats) : 0;
    int Ec = (int)(avail / 16384);
    Ec = (Ec / 16) * 16;                 // rows multiple of 64
    if (Ec > LL) Ec = LL;
    if (Ec < 16) Ec = 16;                // below this, nothing fits anyway

    const size_t rmax = (size_t)4 * Ec;  // max rows per chunk
    float* buf0 = cbase;                 // node_f -> ffn_out
    float* buf1 = buf0 + rmax * CC;      // q -> ctx
    float* buf2 = buf1 + rmax * CC;      // k -> attn_out
    float* buf3 = buf2 + rmax * CC;      // v -> out1
    float* bufH = buf3 + rmax * CC;      // FFN hidden

    GatherArgs ga{x, ts, W_temb, b_temb, eattr, ei};
    const dim3 blk(256);

    // Fold q/k/v projections into the input-feature projections
    comb_w<<<dim3(1024), blk, 0, stream>>>(Wq, W_node,  W_nq, 512);
    comb_b<<<dim3(2),    blk, 0, stream>>>(Wq, b_node,  bq,   b_nq);
    comb_w<<<dim3(256),  blk, 0, stream>>>(Wk, W_timef, W_tk, 128);
    comb_b<<<dim3(2),    blk, 0, stream>>>(Wk, b_timef, bk,   b_tk);
    comb_w<<<dim3(256),  blk, 0, stream>>>(Wv, W_edge,  W_ev, 128);
    comb_b<<<dim3(2),    blk, 0, stream>>>(Wv, b_edge,  bv,   b_ev);

    for (int e0 = 0; e0 < LL; e0 += Ec) {
        int ec = LL - e0; if (ec > Ec) ec = Ec;   // LL and Ec are multiples of 16
        const int rows = 4 * ec;
        const dim3 gy(8, rows / 64);

        // node_f ; q ; k ; v
        gemm_kernel<SRC_NODE, false><<<gy, blk, 0, stream>>>(nullptr, W_node, b_node, buf0, 512, CC, e0, ec, ga);
        gemm_kernel<SRC_NODE, false><<<gy, blk, 0, stream>>>(nullptr, W_nq,   b_nq,   buf1, 512, CC, e0, ec, ga);
        gemm_kernel<SRC_TIME, false><<<gy, blk, 0, stream>>>(nullptr, W_tk,   b_tk,   buf2, 128, CC, e0, ec, ga);
        gemm_kernel<SRC_EDGE, false><<<gy, blk, 0, stream>>>(nullptr, W_ev,   b_ev,   buf3, 128, CC, e0, ec, ga);

        // batch-axis attention: ctx overwrites q (buf1)
        attn_kernel<<<dim3(ec), dim3(512), 0, stream>>>(buf1, buf2, buf3, ec);

        // attn_out = ctx @ Wo^T + bo -> buf2 ; out1 = LN(node_f + attn_out) -> buf3
        gemm_kernel<SRC_PLAIN, false><<<gy, blk, 0, stream>>>(buf1, Wo, bo, buf2, 512, CC, e0, ec, ga);
        ln_add_kernel<false><<<dim3(rows), blk, 0, stream>>>(buf0, buf2, g1, be1, buf3, e0, ec);

        // FFN: hidden = gelu(out1 @ W1^T + b1) ; ffn = hidden @ W2^T + b2 -> buf0
        gemm_kernel<SRC_PLAIN, true ><<<dim3(C4 / 64, rows / 64), blk, 0, stream>>>(buf3, W1, b1, bufH, 512, C4, e0, ec, ga);
        gemm_kernel<SRC_PLAIN, false><<<dim3(CC / 64, rows / 64), blk, 0, stream>>>(bufH, W2, b2, buf0, C4, CC, e0, ec, ga);

        // out2 = LN(out1 + ffn) -> d_out (mapped to global rows)
        ln_add_kernel<true><<<dim3(rows), blk, 0, stream>>>(buf3, buf0, g2, be2, out, e0, ec);
    }
}

// Round 3
// 1573.717 us; speedup vs baseline: 4.5328x; 4.5328x over previous
//
#include <hip/hip_runtime.h>
#include <math.h>

#define BB 4
#define NN 2048
#define EE 16384
#define LL (EE + NN)      // 18432
#define ND_ 256
#define ED_ 128
#define TD_ 64
#define CC 512
#define HH 8
#define DH_ 64
#define C4 2048

typedef unsigned short u16;
typedef __bf16 bhalf8 __attribute__((ext_vector_type(8)));
typedef float f32x4 __attribute__((ext_vector_type(4)));

struct GatherArgs {
    const float* x;      // (B,N,ND)
    const float* ts;     // (B,N)
    const float* wtemb;  // (TD)
    const float* btemb;  // (TD)
    const float* eattr;  // (B,E,ED)
    const int*   ei;     // (B,2,E)
};

__device__ __forceinline__ u16 f2bf(float f) {
    union { float f; unsigned u; } c; c.f = f;
    const unsigned r = (c.u + 0x7fffu + ((c.u >> 16) & 1u)) >> 16;   // RNE
    return (u16)r;
}

__device__ __forceinline__ float gelu_exact(float v) {
    return 0.5f * v * (1.0f + erff(v * 0.7071067811865475f));
}

#define GLD16(gp, lp) __builtin_amdgcn_global_load_lds( \
    (const __attribute__((address_space(1))) unsigned int*)(gp), \
    (__attribute__((address_space(3))) unsigned int*)(lp), 16, 0, 0)

// ---------------------------------------------------------------------------
// bf16 MFMA GEMM (m97 structure): Y[M x N] = A[M x K] @ W[N x K]^T + bias
// 128x128 tile, BK=32, 256 threads = 4 waves (2x2), 4x4 16x16 frags per wave.
// M % 128 == 0, N % 128 == 0, K % 32 == 0. A,W bf16 row-major; Y f32 or bf16.
// ---------------------------------------------------------------------------
template<bool OUTBF16, bool GELU>
__global__ __launch_bounds__(256)
void gemm_mfma(const u16* __restrict__ A, const u16* __restrict__ W,
               const float* __restrict__ bias, void* __restrict__ Yv,
               int N, int K)
{
    __shared__ u16 As[128 * 32];
    __shared__ u16 Ws[128 * 32];
    const int tid  = threadIdx.x;
    const int lane = tid & 63;
    const int wv   = tid >> 6;          // wave 0..3
    const int wr   = wv >> 1;           // wave row (0..1) -> 64 rows
    const int wc   = wv & 1;            // wave col (0..1) -> 64 cols
    const int m0 = blockIdx.y * 128;
    const int n0 = blockIdx.x * 128;

    const size_t sK = (size_t)K;
    const u16* Ag = A + (size_t)(m0 + (tid >> 2)) * sK + (tid & 3) * 8;
    const u16* Wg = W + (size_t)(n0 + (tid >> 2)) * sK + (tid & 3) * 8;
    u16* AsP = &As[tid * 8];
    u16* WsP = &Ws[tid * 8];

    f32x4 acc[4][4] = {};

    const int kb  = (lane >> 4) * 8;    // k offset within BK=32
    const int rlo = lane & 15;

    for (int k0 = 0; k0 < K; k0 += 32) {
        GLD16(Ag + k0,           AsP);
        GLD16(Ag + k0 + 64 * sK, AsP + 64 * 32);
        GLD16(Wg + k0,           WsP);
        GLD16(Wg + k0 + 64 * sK, WsP + 64 * 32);
        __syncthreads();                 // compiler drains vmcnt before barrier

        bhalf8 a[4], b[4];
        #pragma unroll
        for (int i = 0; i < 4; i++) {
            a[i] = *(const bhalf8*)&As[(wr * 64 + i * 16 + rlo) * 32 + kb];
            b[i] = *(const bhalf8*)&Ws[(wc * 64 + i * 16 + rlo) * 32 + kb];
        }
        #pragma unroll
        for (int i = 0; i < 4; i++)
            #pragma unroll
            for (int j = 0; j < 4; j++)
                acc[i][j] = __builtin_amdgcn_mfma_f32_16x16x32_bf16(a[i], b[j], acc[i][j], 0, 0, 0);
        __syncthreads();
    }

    // Epilogue: D col = lane&15, row = (lane>>4)*4 + reg  (m89-verified)
    const int row0 = m0 + wr * 64;
    const int col0 = n0 + wc * 64;
    const int rq   = (lane >> 4) * 4;
    #pragma unroll
    for (int j = 0; j < 4; j++) {
        const int gc = col0 + j * 16 + rlo;
        const float bvv = bias[gc];
        #pragma unroll
        for (int i = 0; i < 4; i++) {
            #pragma unroll
            for (int r = 0; r < 4; r++) {
                const int gr = row0 + i * 16 + rq + r;
                float v = acc[i][j][r] + bvv;
                if constexpr (GELU) v = gelu_exact(v);
                if constexpr (OUTBF16) ((u16*)Yv)[(size_t)gr * N + gc] = f2bf(v);
                else                   ((float*)Yv)[(size_t)gr * N + gc] = v;
            }
        }
    }
}

// ---------------------------------------------------------------------------
// Fused gather + convert prep: builds bf16 A_node (rows x 512),
// A_time (rows x 128), A_edge (rows x 128) for a chunk. One block per row.
// ---------------------------------------------------------------------------
__global__ __launch_bounds__(256)
void prep_kernel(u16* __restrict__ An, u16* __restrict__ At, u16* __restrict__ Ae,
                 int e0, int Ec, GatherArgs ga)
{
    const int r  = blockIdx.x;
    const int b  = r / Ec;
    const int el = r - b * Ec;
    const int ge = e0 + el;
    const int t  = threadIdx.x;

    int isrc, itgt;
    if (ge < EE) {
        isrc = ga.ei[(b * 2 + 0) * EE + ge];
        itgt = ga.ei[(b * 2 + 1) * EE + ge];
    } else {
        isrc = itgt = ge - EE;
    }

    if (t < 128) {
        const int c = t * 4;
        const float* src = (c < ND_) ? (ga.x + ((size_t)b * NN + isrc) * ND_ + c)
                                     : (ga.x + ((size_t)b * NN + itgt) * ND_ + (c - ND_));
        const float4 vv = *(const float4*)src;
        ushort4 ov;
        ov.x = f2bf(vv.x); ov.y = f2bf(vv.y); ov.z = f2bf(vv.z); ov.w = f2bf(vv.w);
        *(ushort4*)(An + (size_t)r * 512 + c) = ov;
    } else if (t < 160) {
        const int c  = (t - 128) * 4;
        const float tt = (c < TD_) ? ga.ts[b * NN + isrc] : ga.ts[b * NN + itgt];
        const int  cb = (c < TD_) ? c : c - TD_;
        ushort4 ov;
        ov.x = f2bf(sinf(tt * ga.wtemb[cb + 0] + ga.btemb[cb + 0]));
        ov.y = f2bf(sinf(tt * ga.wtemb[cb + 1] + ga.btemb[cb + 1]));
        ov.z = f2bf(sinf(tt * ga.wtemb[cb + 2] + ga.btemb[cb + 2]));
        ov.w = f2bf(sinf(tt * ga.wtemb[cb + 3] + ga.btemb[cb + 3]));
        *(ushort4*)(At + (size_t)r * 128 + c) = ov;
    } else if (t < 192) {
        const int c = (t - 160) * 4;
        float4 vv = make_float4(0.f, 0.f, 0.f, 0.f);
        if (ge < EE) vv = *(const float4*)(ga.eattr + ((size_t)b * EE + ge) * ED_ + c);
        ushort4 ov;
        ov.x = f2bf(vv.x); ov.y = f2bf(vv.y); ov.z = f2bf(vv.z); ov.w = f2bf(vv.w);
        *(ushort4*)(Ae + (size_t)r * 128 + c) = ov;
    }
}

// ---------------------------------------------------------------------------
// Weight folding (f32 math, bf16 out):  Wout[c][k] = sum_j Wa[c][j]*Wb[j][k]
// ---------------------------------------------------------------------------
__global__ __launch_bounds__(256)
void comb_w_bf(const float* __restrict__ Wa, const float* __restrict__ Wb,
               u16* __restrict__ Wout, int K)
{
    const int idx  = blockIdx.x * 256 + threadIdx.x;
    const int c    = idx / K;
    const int kcol = idx - c * K;
    float acc = 0.f;
    for (int j = 0; j < CC; j++)
        acc += Wa[c * CC + j] * Wb[j * K + kcol];
    Wout[idx] = f2bf(acc);
}

__global__ __launch_bounds__(256)
void comb_b(const float* __restrict__ Wa, const float* __restrict__ bin,
            const float* __restrict__ ba, float* __restrict__ bout)
{
    const int c = blockIdx.x * 256 + threadIdx.x;
    float acc = ba[c];
    for (int j = 0; j < CC; j++)
        acc += Wa[c * CC + j] * bin[j];
    bout[c] = acc;
}

__global__ __launch_bounds__(256)
void cvt_bf(const float* __restrict__ in, u16* __restrict__ out, int n)
{
    const int i = (blockIdx.x * 256 + threadIdx.x) * 4;
    if (i < n) {
        const float4 v = *(const float4*)(in + i);
        ushort4 ov;
        ov.x = f2bf(v.x); ov.y = f2bf(v.y); ov.z = f2bf(v.z); ov.w = f2bf(v.w);
        *(ushort4*)(out + i) = ov;
    }
}

// ---------------------------------------------------------------------------
// Batch-axis attention: per (edge, head) a 4x4 score matrix. ctx out in bf16.
// ---------------------------------------------------------------------------
__global__ __launch_bounds__(512)
void attn_kernel(const float* __restrict__ q, const float* __restrict__ k,
                 const float* __restrict__ v, u16* __restrict__ ctx, int Ec)
{
    const int e = blockIdx.x;
    const int t = threadIdx.x;
    const int h = t >> 6;
    const int d = t & 63;
    const size_t off = (size_t)h * DH_ + d;

    float qv[4], kv[4], vv[4];
    #pragma unroll
    for (int l = 0; l < 4; l++) {
        const size_t r = ((size_t)(l * Ec + e)) * CC + off;
        qv[l] = q[r]; kv[l] = k[r]; vv[l] = v[r];
    }

    float sc[4][4];
    #pragma unroll
    for (int l = 0; l < 4; l++) {
        #pragma unroll
        for (int m = 0; m < 4; m++) {
            float p = qv[l] * kv[m];
            #pragma unroll
            for (int o = 32; o; o >>= 1) p += __shfl_xor(p, o, 64);
            sc[l][m] = p * 0.125f;
        }
    }

    #pragma unroll
    for (int l = 0; l < 4; l++) {
        const float mx = fmaxf(fmaxf(sc[l][0], sc[l][1]), fmaxf(sc[l][2], sc[l][3]));
        float a[4], s = 0.f;
        #pragma unroll
        for (int m = 0; m < 4; m++) { a[m] = expf(sc[l][m] - mx); s += a[m]; }
        const float inv = 1.0f / s;
        float c = 0.f;
        #pragma unroll
        for (int m = 0; m < 4; m++) c += a[m] * inv * vv[m];
        ctx[((size_t)(l * Ec + e)) * CC + off] = f2bf(c);
    }
}

// ---------------------------------------------------------------------------
// ln1: y = LN(nodef + attn_out); y -> d_out (global rows, f32) AND bf16 local
// ---------------------------------------------------------------------------
__global__ __launch_bounds__(256)
void ln1_kernel(const float* __restrict__ A, const float* __restrict__ Bv,
                const float* __restrict__ g, const float* __restrict__ be,
                float* __restrict__ outf, u16* __restrict__ outb, int e0, int Ec)
{
    const int r = blockIdx.x;
    const size_t base = (size_t)r * CC;
    const int t = threadIdx.x;

    const float v0 = A[base + t]       + Bv[base + t];
    const float v1 = A[base + t + 256] + Bv[base + t + 256];

    __shared__ float red[4];
    float s = v0 + v1;
    #pragma unroll
    for (int o = 32; o; o >>= 1) s += __shfl_xor(s, o, 64);
    const int wid = t >> 6, lane = t & 63;
    if (lane == 0) red[wid] = s;
    __syncthreads();
    const float mean = (red[0] + red[1] + red[2] + red[3]) * (1.0f / 512.0f);

    const float d0 = v0 - mean, d1 = v1 - mean;
    float vs = d0 * d0 + d1 * d1;
    #pragma unroll
    for (int o = 32; o; o >>= 1) vs += __shfl_xor(vs, o, 64);
    __syncthreads();
    if (lane == 0) red[wid] = vs;
    __syncthreads();
    const float var = (red[0] + red[1] + red[2] + red[3]) * (1.0f / 512.0f);
    const float rstd = rsqrtf(var + 1e-5f);

    const float y0 = d0 * rstd * g[t]       + be[t];
    const float y1 = d1 * rstd * g[t + 256] + be[t + 256];

    const int b  = r / Ec;
    const int el = r - b * Ec;
    const size_t gbase = ((size_t)b * LL + e0 + el) * CC;
    outf[gbase + t]       = y0;
    outf[gbase + t + 256] = y1;
    outb[base + t]        = f2bf(y0);
    outb[base + t + 256]  = f2bf(y1);
}

// ---------------------------------------------------------------------------
// ln2: d_out[gr] = LN(d_out[gr] + ffn[r])  (reads both before writing)
// ---------------------------------------------------------------------------
__global__ __launch_bounds__(256)
void ln2_kernel(const float* __restrict__ ffn,
                const float* __restrict__ g, const float* __restrict__ be,
                float* __restrict__ io, int e0, int Ec)
{
    const int r = blockIdx.x;
    const int t = threadIdx.x;
    const int b  = r / Ec;
    const int el = r - b * Ec;
    const size_t gbase = ((size_t)b * LL + e0 + el) * CC;
    const size_t lbase = (size_t)r * CC;

    const float v0 = io[gbase + t]       + ffn[lbase + t];
    const float v1 = io[gbase + t + 256] + ffn[lbase + t + 256];

    __shared__ float red[4];
    float s = v0 + v1;
    #pragma unroll
    for (int o = 32; o; o >>= 1) s += __shfl_xor(s, o, 64);
    const int wid = t >> 6, lane = t & 63;
    if (lane == 0) red[wid] = s;
    __syncthreads();
    const float mean = (red[0] + red[1] + red[2] + red[3]) * (1.0f / 512.0f);

    const float d0 = v0 - mean, d1 = v1 - mean;
    float vs = d0 * d0 + d1 * d1;
    #pragma unroll
    for (int o = 32; o; o >>= 1) vs += __shfl_xor(vs, o, 64);
    __syncthreads();
    if (lane == 0) red[wid] = vs;
    __syncthreads();
    const float var = (red[0] + red[1] + red[2] + red[3]) * (1.0f / 512.0f);
    const float rstd = rsqrtf(var + 1e-5f);

    io[gbase + t]       = d0 * rstd * g[t]       + be[t];
    io[gbase + t + 256] = d1 * rstd * g[t + 256] + be[t + 256];
}

// ---------------------------------------------------------------------------
extern "C" void kernel_launch(void* const* d_in, const int* in_sizes, int n_in,
                              void* d_out, int out_size, void* d_ws, size_t ws_size,
                              hipStream_t stream)
{
    const float* x       = (const float*)d_in[0];
    const float* eattr   = (const float*)d_in[1];
    const float* ts      = (const float*)d_in[2];
    const float* W_node  = (const float*)d_in[3];
    const float* b_node  = (const float*)d_in[4];
    const float* W_temb  = (const float*)d_in[5];
    const float* b_temb  = (const float*)d_in[6];
    const float* W_timef = (const float*)d_in[7];
    const float* b_timef = (const float*)d_in[8];
    const float* W_edge  = (const float*)d_in[9];
    const float* b_edge  = (const float*)d_in[10];
    const float* Wq      = (const float*)d_in[11];
    const float* bq      = (const float*)d_in[12];
    const float* Wk      = (const float*)d_in[13];
    const float* bk      = (const float*)d_in[14];
    const float* Wv      = (const float*)d_in[15];
    const float* bv      = (const float*)d_in[16];
    const float* Wo      = (const float*)d_in[17];
    const float* bo      = (const float*)d_in[18];
    const float* W1      = (const float*)d_in[19];
    const float* b1      = (const float*)d_in[20];
    const float* W2      = (const float*)d_in[21];
    const float* b2      = (const float*)d_in[22];
    const float* g1      = (const float*)d_in[23];
    const float* be1     = (const float*)d_in[24];
    const float* g2      = (const float*)d_in[25];
    const float* be2     = (const float*)d_in[26];
    const int*   ei      = (const int*)d_in[27];

    float* out = (float*)d_out;

    // ---- weight region (bf16) at front of ws ----
    u16* wnode = (u16*)d_ws;            // 512*512
    u16* wnq   = wnode + 262144;        // 512*512 folded Wq@W_node
    u16* wtk   = wnq + 262144;          // 512*128 folded Wk@W_timef
    u16* wev   = wtk + 65536;           // 512*128 folded Wv@W_edge
    u16* wo    = wev + 65536;           // 512*512
    u16* w1b   = wo + 262144;           // 2048*512
    u16* w2b   = w1b + 1048576;         // 512*2048
    float* bnq = (float*)(w2b + 1048576);
    float* btk = bnq + 512;
    float* bev = btk + 512;
    char*  cbase = (char*)(bev + 512);
    const size_t fixedB = (size_t)(cbase - (char*)d_ws);

    // ---- chunk sizing: 38912 bytes per edge ----
    const size_t availB = (ws_size > fixedB) ? (ws_size - fixedB) : 0;
    int Ec = (int)(availB / 38912);
    Ec = (Ec / 32) * 32;
    if (Ec > LL) Ec = LL;
    if (Ec < 32) Ec = 32;

    const size_t rmax = (size_t)4 * Ec;
    u16*   An    = (u16*)cbase;             // rows x 512 bf16 (-> ctx -> out1_bf16)
    u16*   At    = An + rmax * 512;         // rows x 128 bf16
    u16*   Ae    = At + rmax * 128;         // rows x 128 bf16
    float* nodef = (float*)(Ae + rmax * 128);
    float* qb    = nodef + rmax * 512;      // q -> attn_out
    float* kb    = qb + rmax * 512;         // k -> ffn
    float* vb    = kb + rmax * 512;         // v
    u16*   hid   = (u16*)nodef;             // rows x 2048 bf16, overlays [nodef|qb]

    GatherArgs ga{x, ts, W_temb, b_temb, eattr, ei};
    const dim3 blk(256);

    // ---- weight prep ----
    cvt_bf   <<<dim3(256),  blk, 0, stream>>>(W_node, wnode, 262144);
    comb_w_bf<<<dim3(1024), blk, 0, stream>>>(Wq, W_node,  wnq, 512);
    comb_w_bf<<<dim3(256),  blk, 0, stream>>>(Wk, W_timef, wtk, 128);
    comb_w_bf<<<dim3(256),  blk, 0, stream>>>(Wv, W_edge,  wev, 128);
    cvt_bf   <<<dim3(256),  blk, 0, stream>>>(Wo, wo,  262144);
    cvt_bf   <<<dim3(1024), blk, 0, stream>>>(W1, w1b, 1048576);
    cvt_bf   <<<dim3(1024), blk, 0, stream>>>(W2, w2b, 1048576);
    comb_b   <<<dim3(2),    blk, 0, stream>>>(Wq, b_node,  bq, bnq);
    comb_b   <<<dim3(2),    blk, 0, stream>>>(Wk, b_timef, bk, btk);
    comb_b   <<<dim3(2),    blk, 0, stream>>>(Wv, b_edge,  bv, bev);

    for (int e0 = 0; e0 < LL; e0 += Ec) {
        int ec = LL - e0; if (ec > Ec) ec = Ec;   // multiples of 32
        const int rows = 4 * ec;
        const dim3 gn(4, rows / 128);             // N = 512

        prep_kernel<<<dim3(rows), blk, 0, stream>>>(An, At, Ae, e0, ec, ga);

        gemm_mfma<false, false><<<gn, blk, 0, stream>>>(An, wnode, b_node, nodef, 512, 512);
        gemm_mfma<false, false><<<gn, blk, 0, stream>>>(An, wnq,   bnq,    qb,    512, 512);
        gemm_mfma<false, false><<<gn, blk, 0, stream>>>(At, wtk,   btk,    kb,    512, 128);
        gemm_mfma<false, false><<<gn, blk, 0, stream>>>(Ae, wev,   bev,    vb,    512, 128);

        attn_kernel<<<dim3(ec), dim3(512), 0, stream>>>(qb, kb, vb, An /*ctx*/, ec);

        gemm_mfma<false, false><<<gn, blk, 0, stream>>>(An, wo, bo, qb /*attn_out*/, 512, 512);
        ln1_kernel<<<dim3(rows), blk, 0, stream>>>(nodef, qb, g1, be1, out, An /*out1 bf16*/, e0, ec);

        gemm_mfma<true, true ><<<dim3(16, rows / 128), blk, 0, stream>>>(An, w1b, b1, hid, 2048, 512);
        gemm_mfma<false, false><<<gn, blk, 0, stream>>>(hid, w2b, b2, kb /*ffn*/, 512, 2048);

        ln2_kernel<<<dim3(rows), blk, 0, stream>>>(kb, g2, be2, out, e0, ec);
    }
}

// Round 4
// 1559.356 us; speedup vs baseline: 4.5745x; 1.0092x over previous
//
#include <hip/hip_runtime.h>
#include <math.h>

#define BB 4
#define NN 2048
#define EE 16384
#define LL (EE + NN)      // 18432
#define ND_ 256
#define ED_ 128
#define TD_ 64
#define CC 512
#define HH 8
#define DH_ 64
#define C4 2048

typedef unsigned short u16;
typedef __bf16 bhalf8 __attribute__((ext_vector_type(8)));
typedef float f32x4 __attribute__((ext_vector_type(4)));

struct GatherArgs {
    const float* x;      // (B,N,ND)
    const float* ts;     // (B,N)
    const float* wtemb;  // (TD)
    const float* btemb;  // (TD)
    const float* eattr;  // (B,E,ED)
    const int*   ei;     // (B,2,E)
};

__device__ __forceinline__ u16 f2bf(float f) {
    union { float f; unsigned u; } c; c.f = f;
    const unsigned r = (c.u + 0x7fffu + ((c.u >> 16) & 1u)) >> 16;   // RNE
    return (u16)r;
}
__device__ __forceinline__ float bf2f(u16 u) {
    union { unsigned u; float f; } c; c.u = ((unsigned)u) << 16; return c.f;
}
__device__ __forceinline__ float gelu_exact(float v) {
    return 0.5f * v * (1.0f + erff(v * 0.7071067811865475f));
}

#define GLD16(gp, lp) __builtin_amdgcn_global_load_lds( \
    (const __attribute__((address_space(1))) unsigned int*)(gp), \
    (__attribute__((address_space(3))) unsigned int*)(lp), 16, 0, 0)

// ---------------------------------------------------------------------------
// bf16 MFMA GEMM: Y[M x N](bf16) = A[M x K](bf16) @ W[N x K]^T + bias(f32)
// 128x128 tile, BK=32, 256 thr = 4 waves (2x2), 4x4 16x16 frags per wave.
// Swapped-operand MFMA: D holds 4 consecutive COLS per lane -> ushort4 stores.
// Bijective XCD-chunked block swizzle (m204) for L2 locality.
// ---------------------------------------------------------------------------
template<bool GELU>
__global__ __launch_bounds__(256)
void gemm_mfma(const u16* __restrict__ A, const u16* __restrict__ W,
               const float* __restrict__ bias, u16* __restrict__ Y,
               int N, int K)
{
    __shared__ u16 As[128 * 32];
    __shared__ u16 Ws[128 * 32];

    // XCD swizzle: dispatch-linear id -> contiguous logical range per XCD
    const int o    = blockIdx.y * gridDim.x + blockIdx.x;
    const int nwg  = gridDim.x * gridDim.y;
    const int xcd  = o & 7;
    const int qq   = nwg >> 3, rr = nwg & 7;
    const int wg   = (xcd < rr ? xcd * (qq + 1) : rr * (qq + 1) + (xcd - rr) * qq) + (o >> 3);
    const int bx   = wg % gridDim.x;
    const int by   = wg / gridDim.x;
    const int m0   = by * 128;
    const int n0   = bx * 128;

    const int tid  = threadIdx.x;
    const int lane = tid & 63;
    const int wv   = tid >> 6;
    const int wr   = wv >> 1;           // wave row (64 rows)
    const int wc   = wv & 1;            // wave col (64 cols)

    const size_t sK = (size_t)K;
    const u16* Ag = A + (size_t)(m0 + (tid >> 2)) * sK + (tid & 3) * 8;
    const u16* Wg = W + (size_t)(n0 + (tid >> 2)) * sK + (tid & 3) * 8;
    u16* AsP = &As[tid * 8];
    u16* WsP = &Ws[tid * 8];

    f32x4 acc[4][4] = {};

    const int kb  = (lane >> 4) * 8;
    const int rlo = lane & 15;

    for (int k0 = 0; k0 < K; k0 += 32) {
        GLD16(Ag + k0,           AsP);
        GLD16(Ag + k0 + 64 * sK, AsP + 64 * 32);
        GLD16(Wg + k0,           WsP);
        GLD16(Wg + k0 + 64 * sK, WsP + 64 * 32);
        __syncthreads();

        bhalf8 a[4], b[4];
        #pragma unroll
        for (int i = 0; i < 4; i++) {
            a[i] = *(const bhalf8*)&As[(wr * 64 + i * 16 + rlo) * 32 + kb];
            b[i] = *(const bhalf8*)&Ws[(wc * 64 + i * 16 + rlo) * 32 + kb];
        }
        #pragma unroll
        for (int i = 0; i < 4; i++)
            #pragma unroll
            for (int j = 0; j < 4; j++)   // swapped operands: D transposed
                acc[i][j] = __builtin_amdgcn_mfma_f32_16x16x32_bf16(b[j], a[i], acc[i][j], 0, 0, 0);
        __syncthreads();
    }

    // Epilogue: row = row0+i*16+(lane&15), cols = col0+j*16+(lane>>4)*4+(0..3)
    const int row0 = m0 + wr * 64;
    const int col0 = n0 + wc * 64;
    const int rq   = (lane >> 4) * 4;
    #pragma unroll
    for (int i = 0; i < 4; i++) {
        const int gr = row0 + i * 16 + rlo;
        u16* yrow = Y + (size_t)gr * N;
        #pragma unroll
        for (int j = 0; j < 4; j++) {
            const int gc = col0 + j * 16 + rq;
            const float4 bi = *(const float4*)(bias + gc);
            float v0 = acc[i][j][0] + bi.x;
            float v1 = acc[i][j][1] + bi.y;
            float v2 = acc[i][j][2] + bi.z;
            float v3 = acc[i][j][3] + bi.w;
            if constexpr (GELU) {
                v0 = gelu_exact(v0); v1 = gelu_exact(v1);
                v2 = gelu_exact(v2); v3 = gelu_exact(v3);
            }
            ushort4 ov;
            ov.x = f2bf(v0); ov.y = f2bf(v1); ov.z = f2bf(v2); ov.w = f2bf(v3);
            *(ushort4*)(yrow + gc) = ov;
        }
    }
}

// ---------------------------------------------------------------------------
// Prep: gathered bf16 A_node (rows x 512) and A_kv = [time|edge] (rows x 256)
// ---------------------------------------------------------------------------
__global__ __launch_bounds__(256)
void prep_kernel(u16* __restrict__ An, u16* __restrict__ Akv,
                 int e0, int Ec, GatherArgs ga)
{
    const int r  = blockIdx.x;
    const int b  = r / Ec;
    const int el = r - b * Ec;
    const int ge = e0 + el;
    const int t  = threadIdx.x;

    int isrc, itgt;
    if (ge < EE) {
        isrc = ga.ei[(b * 2 + 0) * EE + ge];
        itgt = ga.ei[(b * 2 + 1) * EE + ge];
    } else {
        isrc = itgt = ge - EE;
    }

    if (t < 128) {
        const int c = t * 4;
        const float* src = (c < ND_) ? (ga.x + ((size_t)b * NN + isrc) * ND_ + c)
                                     : (ga.x + ((size_t)b * NN + itgt) * ND_ + (c - ND_));
        const float4 vv = *(const float4*)src;
        ushort4 ov;
        ov.x = f2bf(vv.x); ov.y = f2bf(vv.y); ov.z = f2bf(vv.z); ov.w = f2bf(vv.w);
        *(ushort4*)(An + (size_t)r * 512 + c) = ov;
    } else if (t < 160) {
        const int c  = (t - 128) * 4;                 // 0..124 (time part)
        const float tt = (c < TD_) ? ga.ts[b * NN + isrc] : ga.ts[b * NN + itgt];
        const int  cb = (c < TD_) ? c : c - TD_;
        ushort4 ov;
        ov.x = f2bf(sinf(tt * ga.wtemb[cb + 0] + ga.btemb[cb + 0]));
        ov.y = f2bf(sinf(tt * ga.wtemb[cb + 1] + ga.btemb[cb + 1]));
        ov.z = f2bf(sinf(tt * ga.wtemb[cb + 2] + ga.btemb[cb + 2]));
        ov.w = f2bf(sinf(tt * ga.wtemb[cb + 3] + ga.btemb[cb + 3]));
        *(ushort4*)(Akv + (size_t)r * 256 + c) = ov;
    } else if (t < 192) {
        const int c = (t - 160) * 4;                  // 0..124 (edge part)
        float4 vv = make_float4(0.f, 0.f, 0.f, 0.f);
        if (ge < EE) vv = *(const float4*)(ga.eattr + ((size_t)b * EE + ge) * ED_ + c);
        ushort4 ov;
        ov.x = f2bf(vv.x); ov.y = f2bf(vv.y); ov.z = f2bf(vv.z); ov.w = f2bf(vv.w);
        *(ushort4*)(Akv + (size_t)r * 256 + 128 + c) = ov;
    }
}

// ---------------------------------------------------------------------------
// Weight folding / conversion helpers
// ---------------------------------------------------------------------------
__global__ __launch_bounds__(256)
void comb_w_bf(const float* __restrict__ Wa, const float* __restrict__ Wb,
               u16* __restrict__ out, int Kin, int ostride)
{   // out[c*ostride + k] = sum_j Wa[c][j] * Wb[j][k], c in [0,512), k in [0,Kin)
    const int idx  = blockIdx.x * 256 + threadIdx.x;
    const int c    = idx / Kin;
    const int kcol = idx - c * Kin;
    float acc = 0.f;
    for (int j = 0; j < CC; j++)
        acc += Wa[c * CC + j] * Wb[j * Kin + kcol];
    out[(size_t)c * ostride + kcol] = f2bf(acc);
}

__global__ __launch_bounds__(256)
void comb_b(const float* __restrict__ Wa, const float* __restrict__ bin,
            const float* __restrict__ ba, float* __restrict__ bout)
{
    const int c = blockIdx.x * 256 + threadIdx.x;
    float acc = ba[c];
    for (int j = 0; j < CC; j++)
        acc += Wa[c * CC + j] * bin[j];
    bout[c] = acc;
}

__global__ __launch_bounds__(256)
void cvt_bf(const float* __restrict__ in, u16* __restrict__ out, int n)
{
    const int i = (blockIdx.x * 256 + threadIdx.x) * 4;
    if (i < n) {
        const float4 v = *(const float4*)(in + i);
        ushort4 ov;
        ov.x = f2bf(v.x); ov.y = f2bf(v.y); ov.z = f2bf(v.z); ov.w = f2bf(v.w);
        *(ushort4*)(out + i) = ov;
    }
}

__global__ __launch_bounds__(256)
void zero_u16(u16* __restrict__ p, int n)
{
    const int i = blockIdx.x * 256 + threadIdx.x;
    if (i < n) p[i] = 0;
}

__global__ __launch_bounds__(256)
void copy_f32(const float* __restrict__ in, float* __restrict__ out, int n)
{
    const int i = blockIdx.x * 256 + threadIdx.x;
    if (i < n) out[i] = in[i];
}

// ---------------------------------------------------------------------------
// Batch-axis attention: per (edge, head) a 4x4 score matrix. All bf16 I/O.
// q = nodq[:,512:1024]; k = kv[:,0:512]; v = kv[:,512:1024]; ctx -> An.
// ---------------------------------------------------------------------------
__global__ __launch_bounds__(512)
void attn_kernel(const u16* __restrict__ nodq, const u16* __restrict__ kv,
                 u16* __restrict__ ctx, int Ec)
{
    const int e = blockIdx.x;
    const int t = threadIdx.x;
    const int h = t >> 6;
    const int d = t & 63;
    const int off = h * DH_ + d;

    float qv[4], kvv[4], vv[4];
    #pragma unroll
    for (int l = 0; l < 4; l++) {
        const size_t r = (size_t)(l * Ec + e);
        qv[l]  = bf2f(nodq[r * 1024 + 512 + off]);
        kvv[l] = bf2f(kv[r * 1024 + off]);
        vv[l]  = bf2f(kv[r * 1024 + 512 + off]);
    }

    float sc[4][4];
    #pragma unroll
    for (int l = 0; l < 4; l++) {
        #pragma unroll
        for (int m = 0; m < 4; m++) {
            float p = qv[l] * kvv[m];
            #pragma unroll
            for (int o = 32; o; o >>= 1) p += __shfl_xor(p, o, 64);
            sc[l][m] = p * 0.125f;
        }
    }

    #pragma unroll
    for (int l = 0; l < 4; l++) {
        const float mx = fmaxf(fmaxf(sc[l][0], sc[l][1]), fmaxf(sc[l][2], sc[l][3]));
        float a[4], s = 0.f;
        #pragma unroll
        for (int m = 0; m < 4; m++) { a[m] = expf(sc[l][m] - mx); s += a[m]; }
        const float inv = 1.0f / s;
        float c = 0.f;
        #pragma unroll
        for (int m = 0; m < 4; m++) c += a[m] * inv * vv[m];
        ctx[(size_t)(l * Ec + e) * 512 + off] = f2bf(c);
    }
}

// ---------------------------------------------------------------------------
// ln1: y = LN(nodef + attn_out); nodef = nodq[:,0:512] bf16, aout bf16.
// Writes d_out f32 (global rows) and out1 bf16 (local, into An).
// ---------------------------------------------------------------------------
__global__ __launch_bounds__(256)
void ln1_kernel(const u16* __restrict__ nodq, const u16* __restrict__ aout,
                const float* __restrict__ g, const float* __restrict__ be,
                float* __restrict__ outf, u16* __restrict__ outb, int e0, int Ec)
{
    const int r = blockIdx.x;
    const int t = threadIdx.x;

    const float v0 = bf2f(nodq[(size_t)r * 1024 + t])       + bf2f(aout[(size_t)r * 512 + t]);
    const float v1 = bf2f(nodq[(size_t)r * 1024 + t + 256]) + bf2f(aout[(size_t)r * 512 + t + 256]);

    __shared__ float red[4];
    float s = v0 + v1;
    #pragma unroll
    for (int o = 32; o; o >>= 1) s += __shfl_xor(s, o, 64);
    const int wid = t >> 6, lane = t & 63;
    if (lane == 0) red[wid] = s;
    __syncthreads();
    const float mean = (red[0] + red[1] + red[2] + red[3]) * (1.0f / 512.0f);

    const float d0 = v0 - mean, d1 = v1 - mean;
    float vs = d0 * d0 + d1 * d1;
    #pragma unroll
    for (int o = 32; o; o >>= 1) vs += __shfl_xor(vs, o, 64);
    __syncthreads();
    if (lane == 0) red[wid] = vs;
    __syncthreads();
    const float var = (red[0] + red[1] + red[2] + red[3]) * (1.0f / 512.0f);
    const float rstd = rsqrtf(var + 1e-5f);

    const float y0 = d0 * rstd * g[t]       + be[t];
    const float y1 = d1 * rstd * g[t + 256] + be[t + 256];

    const int b  = r / Ec;
    const int el = r - b * Ec;
    const size_t gbase = ((size_t)b * LL + e0 + el) * CC;
    outf[gbase + t]       = y0;
    outf[gbase + t + 256] = y1;
    outb[(size_t)r * 512 + t]       = f2bf(y0);
    outb[(size_t)r * 512 + t + 256] = f2bf(y1);
}

// ---------------------------------------------------------------------------
// ln2: d_out[gr] = LN(d_out[gr] + ffn[r]) ; ffn bf16
// ---------------------------------------------------------------------------
__global__ __launch_bounds__(256)
void ln2_kernel(const u16* __restrict__ ffn,
                const float* __restrict__ g, const float* __restrict__ be,
                float* __restrict__ io, int e0, int Ec)
{
    const int r = blockIdx.x;
    const int t = threadIdx.x;
    const int b  = r / Ec;
    const int el = r - b * Ec;
    const size_t gbase = ((size_t)b * LL + e0 + el) * CC;

    const float v0 = io[gbase + t]       + bf2f(ffn[(size_t)r * 512 + t]);
    const float v1 = io[gbase + t + 256] + bf2f(ffn[(size_t)r * 512 + t + 256]);

    __shared__ float red[4];
    float s = v0 + v1;
    #pragma unroll
    for (int o = 32; o; o >>= 1) s += __shfl_xor(s, o, 64);
    const int wid = t >> 6, lane = t & 63;
    if (lane == 0) red[wid] = s;
    __syncthreads();
    const float mean = (red[0] + red[1] + red[2] + red[3]) * (1.0f / 512.0f);

    const float d0 = v0 - mean, d1 = v1 - mean;
    float vs = d0 * d0 + d1 * d1;
    #pragma unroll
    for (int o = 32; o; o >>= 1) vs += __shfl_xor(vs, o, 64);
    __syncthreads();
    if (lane == 0) red[wid] = vs;
    __syncthreads();
    const float var = (red[0] + red[1] + red[2] + red[3]) * (1.0f / 512.0f);
    const float rstd = rsqrtf(var + 1e-5f);

    io[gbase + t]       = d0 * rstd * g[t]       + be[t];
    io[gbase + t + 256] = d1 * rstd * g[t + 256] + be[t + 256];
}

// ---------------------------------------------------------------------------
extern "C" void kernel_launch(void* const* d_in, const int* in_sizes, int n_in,
                              void* d_out, int out_size, void* d_ws, size_t ws_size,
                              hipStream_t stream)
{
    const float* x       = (const float*)d_in[0];
    const float* eattr   = (const float*)d_in[1];
    const float* ts      = (const float*)d_in[2];
    const float* W_node  = (const float*)d_in[3];
    const float* b_node  = (const float*)d_in[4];
    const float* W_temb  = (const float*)d_in[5];
    const float* b_temb  = (const float*)d_in[6];
    const float* W_timef = (const float*)d_in[7];
    const float* b_timef = (const float*)d_in[8];
    const float* W_edge  = (const float*)d_in[9];
    const float* b_edge  = (const float*)d_in[10];
    const float* Wq      = (const float*)d_in[11];
    const float* bq      = (const float*)d_in[12];
    const float* Wk      = (const float*)d_in[13];
    const float* bk      = (const float*)d_in[14];
    const float* Wv      = (const float*)d_in[15];
    const float* bv      = (const float*)d_in[16];
    const float* Wo      = (const float*)d_in[17];
    const float* bo      = (const float*)d_in[18];
    const float* W1      = (const float*)d_in[19];
    const float* b1      = (const float*)d_in[20];
    const float* W2      = (const float*)d_in[21];
    const float* b2      = (const float*)d_in[22];
    const float* g1      = (const float*)d_in[23];
    const float* be1     = (const float*)d_in[24];
    const float* g2      = (const float*)d_in[25];
    const float* be2     = (const float*)d_in[26];
    const int*   ei      = (const int*)d_in[27];

    float* out = (float*)d_out;

    // ---- weight region (bf16) at front of ws ----
    u16* wnq_cat = (u16*)d_ws;              // 1024x512  [W_node ; Wq@W_node]
    u16* wkv_cat = wnq_cat + 524288;        // 1024x256  block-diag [Wk@W_timef | Wv@W_edge]
    u16* wo      = wkv_cat + 262144;        // 512x512
    u16* w1b     = wo + 262144;             // 2048x512
    u16* w2b     = w1b + 1048576;           // 512x2048
    float* bias_nq = (float*)(w2b + 1048576);   // 1024
    float* bias_kv = bias_nq + 1024;            // 1024
    char*  cbase   = (char*)(bias_kv + 1024);
    const size_t fixedB = (size_t)(cbase - (char*)d_ws);

    // ---- chunk sizing: per edge = 4 rows x (512+1024+2048) u16 = 28672 B ----
    const size_t availB = (ws_size > fixedB) ? (ws_size - fixedB) : 0;
    int Ec = (int)(availB / 28672);
    Ec = (Ec / 32) * 32;
    if (Ec > LL) Ec = LL;
    if (Ec < 32) Ec = 32;

    const size_t rmax = (size_t)4 * Ec;
    u16* An   = (u16*)cbase;                // rows x 512  (A_node -> ctx -> out1 -> ffn)
    u16* nodq = An + rmax * 512;            // rows x 1024 [nodef | q]
    u16* R    = nodq + rmax * 1024;         // rows x 2048 overlay region
    u16* Akv  = R;                          // rows x 256
    u16* kv   = R + rmax * 256;             // rows x 1024 [k | v]
    u16* aout = R + rmax * 1280;            // rows x 512  attn_out
    u16* hid  = R;                          // rows x 2048 (after aout dead)

    GatherArgs ga{x, ts, W_temb, b_temb, eattr, ei};
    const dim3 blk(256);

    // ---- weight prep ----
    cvt_bf   <<<dim3(256),  blk, 0, stream>>>(W_node, wnq_cat, 262144);          // rows 0-511
    comb_w_bf<<<dim3(1024), blk, 0, stream>>>(Wq, W_node, wnq_cat + 262144, 512, 512); // rows 512+
    zero_u16 <<<dim3(1024), blk, 0, stream>>>(wkv_cat, 262144);
    comb_w_bf<<<dim3(256),  blk, 0, stream>>>(Wk, W_timef, wkv_cat, 128, 256);   // k rows, cols 0-127
    comb_w_bf<<<dim3(256),  blk, 0, stream>>>(Wv, W_edge, wkv_cat + 512 * 256 + 128, 128, 256); // v rows, cols 128+
    cvt_bf   <<<dim3(256),  blk, 0, stream>>>(Wo, wo,  262144);
    cvt_bf   <<<dim3(1024), blk, 0, stream>>>(W1, w1b, 1048576);
    cvt_bf   <<<dim3(1024), blk, 0, stream>>>(W2, w2b, 1048576);
    copy_f32 <<<dim3(2),    blk, 0, stream>>>(b_node, bias_nq, 512);
    comb_b   <<<dim3(2),    blk, 0, stream>>>(Wq, b_node,  bq, bias_nq + 512);
    comb_b   <<<dim3(2),    blk, 0, stream>>>(Wk, b_timef, bk, bias_kv);
    comb_b   <<<dim3(2),    blk, 0, stream>>>(Wv, b_edge,  bv, bias_kv + 512);

    for (int e0 = 0; e0 < LL; e0 += Ec) {
        int ec = LL - e0; if (ec > Ec) ec = Ec;
        const int rows = 4 * ec;
        const int gy = rows / 128;

        prep_kernel<<<dim3(rows), blk, 0, stream>>>(An, Akv, e0, ec, ga);

        // [nodef|q] = An @ wnq_cat^T ; [k|v] = Akv @ wkv_cat^T
        gemm_mfma<false><<<dim3(8, gy), blk, 0, stream>>>(An,  wnq_cat, bias_nq, nodq, 1024, 512);
        gemm_mfma<false><<<dim3(8, gy), blk, 0, stream>>>(Akv, wkv_cat, bias_kv, kv,   1024, 256);

        attn_kernel<<<dim3(ec), dim3(512), 0, stream>>>(nodq, kv, An /*ctx*/, ec);

        // attn_out = ctx @ Wo^T + bo ; out1 = LN(nodef + attn_out)
        gemm_mfma<false><<<dim3(4, gy), blk, 0, stream>>>(An, wo, bo, aout, 512, 512);
        ln1_kernel<<<dim3(rows), blk, 0, stream>>>(nodq, aout, g1, be1, out, An /*out1*/, e0, ec);

        // FFN
        gemm_mfma<true ><<<dim3(16, gy), blk, 0, stream>>>(An,  w1b, b1, hid, 2048, 512);
        gemm_mfma<false><<<dim3(4, gy),  blk, 0, stream>>>(hid, w2b, b2, An /*ffn*/, 512, 2048);

        ln2_kernel<<<dim3(rows), blk, 0, stream>>>(An, g2, be2, out, e0, ec);
    }
}

// Round 5
// 1436.723 us; speedup vs baseline: 4.9650x; 1.0854x over previous
//
#include <hip/hip_runtime.h>
#include <math.h>

#define BB 4
#define NN 2048
#define EE 16384
#define LL (EE + NN)      // 18432
#define ND_ 256
#define ED_ 128
#define TD_ 64
#define CC 512
#define HH 8
#define DH_ 64
#define C4 2048

typedef unsigned short u16;
typedef unsigned int u32;
typedef __bf16 bhalf8 __attribute__((ext_vector_type(8)));
typedef float f32x4 __attribute__((ext_vector_type(4)));

struct GatherArgs {
    const float* x;      // (B,N,ND)
    const float* ts;     // (B,N)
    const float* wtemb;  // (TD)
    const float* btemb;  // (TD)
    const float* eattr;  // (B,E,ED)
    const int*   ei;     // (B,2,E)
};

__device__ __forceinline__ u16 f2bf(float f) {
    union { float f; unsigned u; } c; c.f = f;
    const unsigned r = (c.u + 0x7fffu + ((c.u >> 16) & 1u)) >> 16;   // RNE
    return (u16)r;
}
__device__ __forceinline__ float bf2f(u16 u) {
    union { unsigned u; float f; } c; c.u = ((unsigned)u) << 16; return c.f;
}
// tanh-form GELU: |err vs exact-erf gelu| ~3e-4, far below bf16 rounding
__device__ __forceinline__ float gelu_fast(float v) {
    const float u = v * (0.7978845608f + 0.0356774081f * v * v);
    const float e = __expf(2.0f * u);
    const float t = 1.0f - 2.0f / (e + 1.0f);
    return 0.5f * v * (1.0f + t);
}

#define GLD16(gp, lp) __builtin_amdgcn_global_load_lds( \
    (const __attribute__((address_space(1))) unsigned int*)(gp), \
    (__attribute__((address_space(3))) unsigned int*)(lp), 16, 0, 0)

// ---------------------------------------------------------------------------
// bf16 MFMA GEMM: Y[M x N](bf16) = A[M x K] @ W[N x K]^T + bias(f32)
// 128x128 tile, BK=32, 4 waves, double-buffered LDS, 2-phase prefetch
// (stage t+1 before compute t; single barrier per iter). Swapped-operand
// MFMA => vectorized ushort4 stores. Bijective XCD swizzle (m204).
// ---------------------------------------------------------------------------
template<bool GELU>
__global__ __launch_bounds__(256)
void gemm_mfma(const u16* __restrict__ A, const u16* __restrict__ W,
               const float* __restrict__ bias, u16* __restrict__ Y,
               int N, int K)
{
    __shared__ u16 As[2][128 * 32];
    __shared__ u16 Ws[2][128 * 32];

    const int o    = blockIdx.y * gridDim.x + blockIdx.x;
    const int nwg  = gridDim.x * gridDim.y;
    const int xcd  = o & 7;
    const int qq   = nwg >> 3, rr = nwg & 7;
    const int wg   = (xcd < rr ? xcd * (qq + 1) : rr * (qq + 1) + (xcd - rr) * qq) + (o >> 3);
    const int bx   = wg % gridDim.x;
    const int by   = wg / gridDim.x;
    const int m0   = by * 128;
    const int n0   = bx * 128;

    const int tid  = threadIdx.x;
    const int lane = tid & 63;
    const int wv   = tid >> 6;
    const int wr   = wv >> 1;
    const int wc   = wv & 1;

    const size_t sK = (size_t)K;
    const u16* Ag = A + (size_t)(m0 + (tid >> 2)) * sK + (tid & 3) * 8;
    const u16* Wg = W + (size_t)(n0 + (tid >> 2)) * sK + (tid & 3) * 8;
    const int ldst = tid * 8;

    f32x4 acc[4][4] = {};
    const int kb  = (lane >> 4) * 8;
    const int rlo = lane & 15;

    // prologue: stage k-tile 0 into buffer 0
    GLD16(Ag,           &As[0][ldst]);
    GLD16(Ag + 64 * sK, &As[0][64 * 32 + ldst]);
    GLD16(Wg,           &Ws[0][ldst]);
    GLD16(Wg + 64 * sK, &Ws[0][64 * 32 + ldst]);
    __syncthreads();

    int cur = 0;
    for (int k0 = 0; k0 < K; k0 += 32) {
        const int nxt = cur ^ 1;
        if (k0 + 32 < K) {                    // stage next tile (overlaps compute)
            const int kk = k0 + 32;
            GLD16(Ag + kk,           &As[nxt][ldst]);
            GLD16(Ag + kk + 64 * sK, &As[nxt][64 * 32 + ldst]);
            GLD16(Wg + kk,           &Ws[nxt][ldst]);
            GLD16(Wg + kk + 64 * sK, &Ws[nxt][64 * 32 + ldst]);
        }
        bhalf8 a[4], b[4];
        #pragma unroll
        for (int i = 0; i < 4; i++) {
            a[i] = *(const bhalf8*)&As[cur][(wr * 64 + i * 16 + rlo) * 32 + kb];
            b[i] = *(const bhalf8*)&Ws[cur][(wc * 64 + i * 16 + rlo) * 32 + kb];
        }
        #pragma unroll
        for (int i = 0; i < 4; i++)
            #pragma unroll
            for (int j = 0; j < 4; j++)   // swapped operands: D transposed
                acc[i][j] = __builtin_amdgcn_mfma_f32_16x16x32_bf16(b[j], a[i], acc[i][j], 0, 0, 0);
        __syncthreads();                  // drains vmcnt (next tile) + readers of cur
        cur = nxt;
    }

    const int row0 = m0 + wr * 64;
    const int col0 = n0 + wc * 64;
    const int rq   = (lane >> 4) * 4;
    #pragma unroll
    for (int i = 0; i < 4; i++) {
        const int gr = row0 + i * 16 + rlo;
        u16* yrow = Y + (size_t)gr * N;
        #pragma unroll
        for (int j = 0; j < 4; j++) {
            const int gc = col0 + j * 16 + rq;
            const float4 bi = *(const float4*)(bias + gc);
            float v0 = acc[i][j][0] + bi.x;
            float v1 = acc[i][j][1] + bi.y;
            float v2 = acc[i][j][2] + bi.z;
            float v3 = acc[i][j][3] + bi.w;
            if constexpr (GELU) {
                v0 = gelu_fast(v0); v1 = gelu_fast(v1);
                v2 = gelu_fast(v2); v3 = gelu_fast(v3);
            }
            ushort4 ov;
            ov.x = f2bf(v0); ov.y = f2bf(v1); ov.z = f2bf(v2); ov.w = f2bf(v3);
            *(ushort4*)(yrow + gc) = ov;
        }
    }
}

// ---------------------------------------------------------------------------
// Prep: row order r = 4*edge_local + batch. Builds bf16 A_node (rows x 512)
// and A_kv = [time|edge] (rows x 256).
// ---------------------------------------------------------------------------
__global__ __launch_bounds__(256)
void prep_kernel(u16* __restrict__ An, u16* __restrict__ Akv,
                 int e0, GatherArgs ga)
{
    const int r  = blockIdx.x;
    const int el = r >> 2;
    const int b  = r & 3;
    const int ge = e0 + el;
    const int t  = threadIdx.x;

    int isrc, itgt;
    if (ge < EE) {
        isrc = ga.ei[(b * 2 + 0) * EE + ge];
        itgt = ga.ei[(b * 2 + 1) * EE + ge];
    } else {
        isrc = itgt = ge - EE;
    }

    if (t < 128) {
        const int c = t * 4;
        const float* src = (c < ND_) ? (ga.x + ((size_t)b * NN + isrc) * ND_ + c)
                                     : (ga.x + ((size_t)b * NN + itgt) * ND_ + (c - ND_));
        const float4 vv = *(const float4*)src;
        ushort4 ov;
        ov.x = f2bf(vv.x); ov.y = f2bf(vv.y); ov.z = f2bf(vv.z); ov.w = f2bf(vv.w);
        *(ushort4*)(An + (size_t)r * 512 + c) = ov;
    } else if (t < 160) {
        const int c  = (t - 128) * 4;
        const float tt = (c < TD_) ? ga.ts[b * NN + isrc] : ga.ts[b * NN + itgt];
        const int  cb = (c < TD_) ? c : c - TD_;
        ushort4 ov;
        ov.x = f2bf(sinf(tt * ga.wtemb[cb + 0] + ga.btemb[cb + 0]));
        ov.y = f2bf(sinf(tt * ga.wtemb[cb + 1] + ga.btemb[cb + 1]));
        ov.z = f2bf(sinf(tt * ga.wtemb[cb + 2] + ga.btemb[cb + 2]));
        ov.w = f2bf(sinf(tt * ga.wtemb[cb + 3] + ga.btemb[cb + 3]));
        *(ushort4*)(Akv + (size_t)r * 256 + c) = ov;
    } else if (t < 192) {
        const int c = (t - 160) * 4;
        float4 vv = make_float4(0.f, 0.f, 0.f, 0.f);
        if (ge < EE) vv = *(const float4*)(ga.eattr + ((size_t)b * EE + ge) * ED_ + c);
        ushort4 ov;
        ov.x = f2bf(vv.x); ov.y = f2bf(vv.y); ov.z = f2bf(vv.z); ov.w = f2bf(vv.w);
        *(ushort4*)(Akv + (size_t)r * 256 + 128 + c) = ov;
    }
}

// ---------------------------------------------------------------------------
// Weight folding / conversion helpers
// ---------------------------------------------------------------------------
__global__ __launch_bounds__(256)
void comb_w_bf(const float* __restrict__ Wa, const float* __restrict__ Wb,
               u16* __restrict__ out, int Kin, int ostride)
{
    const int idx  = blockIdx.x * 256 + threadIdx.x;
    const int c    = idx / Kin;
    const int kcol = idx - c * Kin;
    float acc = 0.f;
    for (int j = 0; j < CC; j++)
        acc += Wa[c * CC + j] * Wb[j * Kin + kcol];
    out[(size_t)c * ostride + kcol] = f2bf(acc);
}

__global__ __launch_bounds__(256)
void comb_b(const float* __restrict__ Wa, const float* __restrict__ bin,
            const float* __restrict__ ba, float* __restrict__ bout)
{
    const int c = blockIdx.x * 256 + threadIdx.x;
    float acc = ba[c];
    for (int j = 0; j < CC; j++)
        acc += Wa[c * CC + j] * bin[j];
    bout[c] = acc;
}

__global__ __launch_bounds__(256)
void cvt_bf(const float* __restrict__ in, u16* __restrict__ out, int n)
{
    const int i = (blockIdx.x * 256 + threadIdx.x) * 4;
    if (i < n) {
        const float4 v = *(const float4*)(in + i);
        ushort4 ov;
        ov.x = f2bf(v.x); ov.y = f2bf(v.y); ov.z = f2bf(v.z); ov.w = f2bf(v.w);
        *(ushort4*)(out + i) = ov;
    }
}

__global__ __launch_bounds__(256)
void zero_u16(u16* __restrict__ p, int n)
{
    const int i = blockIdx.x * 256 + threadIdx.x;
    if (i < n) p[i] = 0;
}

__global__ __launch_bounds__(256)
void copy_f32(const float* __restrict__ in, float* __restrict__ out, int n)
{
    const int i = blockIdx.x * 256 + threadIdx.x;
    if (i < n) out[i] = in[i];
}

// ---------------------------------------------------------------------------
// Batch-axis attention, rows 4e..4e+3 adjacent. Block = 4 edges x 64 lanes.
// lane: h = lane>>3 (head), oc = lane&7 (8-elem octet of the 64-dim head).
// Fully vectorized uint4 loads; octet shuffle reduce; ctx (bf16) -> An.
// ---------------------------------------------------------------------------
__global__ __launch_bounds__(256)
void attn_kernel(const u16* __restrict__ nodq, const u16* __restrict__ kv,
                 u16* __restrict__ ctx)
{
    const int e    = blockIdx.x * 4 + (threadIdx.x >> 6);
    const int lane = threadIdx.x & 63;
    const int off  = (lane >> 3) * 64 + (lane & 7) * 8;   // u16 offset in row

    float qf[4][8], kf[4][8], vf[4][8];
    #pragma unroll
    for (int l = 0; l < 4; l++) {
        const size_t rq = (size_t)(4 * e + l) * 1024;
        const uint4 qv = *(const uint4*)(nodq + rq + 512 + off);
        const uint4 kx = *(const uint4*)(kv + rq + off);
        const uint4 vx = *(const uint4*)(kv + rq + 512 + off);
        const u32 qa[4] = {qv.x, qv.y, qv.z, qv.w};
        const u32 ka[4] = {kx.x, kx.y, kx.z, kx.w};
        const u32 va[4] = {vx.x, vx.y, vx.z, vx.w};
        #pragma unroll
        for (int p = 0; p < 4; p++) {
            qf[l][2*p] = bf2f((u16)qa[p]); qf[l][2*p+1] = bf2f((u16)(qa[p] >> 16));
            kf[l][2*p] = bf2f((u16)ka[p]); kf[l][2*p+1] = bf2f((u16)(ka[p] >> 16));
            vf[l][2*p] = bf2f((u16)va[p]); vf[l][2*p+1] = bf2f((u16)(va[p] >> 16));
        }
    }

    float sc[4][4];
    #pragma unroll
    for (int l = 0; l < 4; l++) {
        #pragma unroll
        for (int m = 0; m < 4; m++) {
            float p = 0.f;
            #pragma unroll
            for (int d = 0; d < 8; d++) p += qf[l][d] * kf[m][d];
            p += __shfl_xor(p, 1, 64);
            p += __shfl_xor(p, 2, 64);
            p += __shfl_xor(p, 4, 64);
            sc[l][m] = p * 0.125f;
        }
    }

    #pragma unroll
    for (int l = 0; l < 4; l++) {
        const float mx = fmaxf(fmaxf(sc[l][0], sc[l][1]), fmaxf(sc[l][2], sc[l][3]));
        float a[4], s = 0.f;
        #pragma unroll
        for (int m = 0; m < 4; m++) { a[m] = __expf(sc[l][m] - mx); s += a[m]; }
        const float inv = 1.0f / s;
        float cv[8];
        #pragma unroll
        for (int d = 0; d < 8; d++) {
            cv[d] = (a[0] * vf[0][d] + a[1] * vf[1][d] +
                     a[2] * vf[2][d] + a[3] * vf[3][d]) * inv;
        }
        ushort4 o0, o1;
        o0.x = f2bf(cv[0]); o0.y = f2bf(cv[1]); o0.z = f2bf(cv[2]); o0.w = f2bf(cv[3]);
        o1.x = f2bf(cv[4]); o1.y = f2bf(cv[5]); o1.z = f2bf(cv[6]); o1.w = f2bf(cv[7]);
        u16* crow = ctx + (size_t)(4 * e + l) * 512 + off;
        *(ushort4*)crow       = o0;
        *(ushort4*)(crow + 4) = o1;
    }
}

// ---------------------------------------------------------------------------
// ln1: out1 = LN(nodef + attn_out) -> bf16 only (256 thr, 2 cols/thread)
// ---------------------------------------------------------------------------
__global__ __launch_bounds__(256)
void ln1_kernel(const u16* __restrict__ nodq, const u16* __restrict__ aout,
                const float* __restrict__ g, const float* __restrict__ be,
                u16* __restrict__ outb)
{
    const int r = blockIdx.x;
    const int t = threadIdx.x;
    const int c = t * 2;

    const u32 nf = *(const u32*)(nodq + (size_t)r * 1024 + c);
    const u32 ao = *(const u32*)(aout + (size_t)r * 512 + c);
    const float v0 = bf2f((u16)nf) + bf2f((u16)ao);
    const float v1 = bf2f((u16)(nf >> 16)) + bf2f((u16)(ao >> 16));

    __shared__ float red[4];
    float s = v0 + v1;
    #pragma unroll
    for (int o = 32; o; o >>= 1) s += __shfl_xor(s, o, 64);
    const int wid = t >> 6, lane = t & 63;
    if (lane == 0) red[wid] = s;
    __syncthreads();
    const float mean = (red[0] + red[1] + red[2] + red[3]) * (1.0f / 512.0f);

    const float d0 = v0 - mean, d1 = v1 - mean;
    float vs = d0 * d0 + d1 * d1;
    #pragma unroll
    for (int o = 32; o; o >>= 1) vs += __shfl_xor(vs, o, 64);
    __syncthreads();
    if (lane == 0) red[wid] = vs;
    __syncthreads();
    const float var = (red[0] + red[1] + red[2] + red[3]) * (1.0f / 512.0f);
    const float rstd = rsqrtf(var + 1e-5f);

    const float y0 = d0 * rstd * g[c]     + be[c];
    const float y1 = d1 * rstd * g[c + 1] + be[c + 1];
    ushort2 ov; ov.x = f2bf(y0); ov.y = f2bf(y1);
    *(ushort2*)(outb + (size_t)r * 512 + c) = ov;
}

// ---------------------------------------------------------------------------
// ln2: d_out[grow] = LN(out1 + ffn) (f32 out; sole writer of d_out)
// ---------------------------------------------------------------------------
__global__ __launch_bounds__(256)
void ln2_kernel(const u16* __restrict__ out1, const u16* __restrict__ ffn,
                const float* __restrict__ g, const float* __restrict__ be,
                float* __restrict__ out, int e0)
{
    const int r = blockIdx.x;
    const int t = threadIdx.x;
    const int c = t * 2;

    const u32 o1 = *(const u32*)(out1 + (size_t)r * 512 + c);
    const u32 ff = *(const u32*)(ffn  + (size_t)r * 512 + c);
    const float v0 = bf2f((u16)o1) + bf2f((u16)ff);
    const float v1 = bf2f((u16)(o1 >> 16)) + bf2f((u16)(ff >> 16));

    __shared__ float red[4];
    float s = v0 + v1;
    #pragma unroll
    for (int o = 32; o; o >>= 1) s += __shfl_xor(s, o, 64);
    const int wid = t >> 6, lane = t & 63;
    if (lane == 0) red[wid] = s;
    __syncthreads();
    const float mean = (red[0] + red[1] + red[2] + red[3]) * (1.0f / 512.0f);

    const float d0 = v0 - mean, d1 = v1 - mean;
    float vs = d0 * d0 + d1 * d1;
    #pragma unroll
    for (int o = 32; o; o >>= 1) vs += __shfl_xor(vs, o, 64);
    __syncthreads();
    if (lane == 0) red[wid] = vs;
    __syncthreads();
    const float var = (red[0] + red[1] + red[2] + red[3]) * (1.0f / 512.0f);
    const float rstd = rsqrtf(var + 1e-5f);

    const int el = r >> 2;
    const int b  = r & 3;
    float2 ov;
    ov.x = d0 * rstd * g[c]     + be[c];
    ov.y = d1 * rstd * g[c + 1] + be[c + 1];
    *(float2*)(out + ((size_t)b * LL + e0 + el) * CC + c) = ov;
}

// ---------------------------------------------------------------------------
extern "C" void kernel_launch(void* const* d_in, const int* in_sizes, int n_in,
                              void* d_out, int out_size, void* d_ws, size_t ws_size,
                              hipStream_t stream)
{
    const float* x       = (const float*)d_in[0];
    const float* eattr   = (const float*)d_in[1];
    const float* ts      = (const float*)d_in[2];
    const float* W_node  = (const float*)d_in[3];
    const float* b_node  = (const float*)d_in[4];
    const float* W_temb  = (const float*)d_in[5];
    const float* b_temb  = (const float*)d_in[6];
    const float* W_timef = (const float*)d_in[7];
    const float* b_timef = (const float*)d_in[8];
    const float* W_edge  = (const float*)d_in[9];
    const float* b_edge  = (const float*)d_in[10];
    const float* Wq      = (const float*)d_in[11];
    const float* bq      = (const float*)d_in[12];
    const float* Wk      = (const float*)d_in[13];
    const float* bk      = (const float*)d_in[14];
    const float* Wv      = (const float*)d_in[15];
    const float* bv      = (const float*)d_in[16];
    const float* Wo      = (const float*)d_in[17];
    const float* bo      = (const float*)d_in[18];
    const float* W1      = (const float*)d_in[19];
    const float* b1      = (const float*)d_in[20];
    const float* W2      = (const float*)d_in[21];
    const float* b2      = (const float*)d_in[22];
    const float* g1      = (const float*)d_in[23];
    const float* be1     = (const float*)d_in[24];
    const float* g2      = (const float*)d_in[25];
    const float* be2     = (const float*)d_in[26];
    const int*   ei      = (const int*)d_in[27];

    float* out = (float*)d_out;

    // ---- weight region (bf16) at front of ws ----
    u16* wnq_cat = (u16*)d_ws;              // 1024x512  [W_node ; Wq@W_node]
    u16* wkv_cat = wnq_cat + 524288;        // 1024x256  block-diag [Wk@W_timef | Wv@W_edge]
    u16* wo      = wkv_cat + 262144;        // 512x512
    u16* w1b     = wo + 262144;             // 2048x512
    u16* w2b     = w1b + 1048576;           // 512x2048
    float* bias_nq = (float*)(w2b + 1048576);   // 1024
    float* bias_kv = bias_nq + 1024;            // 1024
    char*  cbase   = (char*)(bias_kv + 1024);
    const size_t fixedB = (size_t)(cbase - (char*)d_ws);

    // ---- chunk sizing: per edge = 4 rows x 4096 u16 = 32768 B ----
    const size_t availB = (ws_size > fixedB) ? (ws_size - fixedB) : 0;
    int Ec = (int)(availB / 32768);
    Ec = (Ec / 32) * 32;
    if (Ec > LL) Ec = LL;
    if (Ec < 32) Ec = 32;

    const size_t rmax = (size_t)4 * Ec;
    u16* An   = (u16*)cbase;                // rows x 512  (A_node -> ctx -> out1)
    u16* nodq = An + rmax * 512;            // rows x 1024 [nodef | q]
    u16* R    = nodq + rmax * 1024;         // rows x 2048 overlay
    u16* Akv  = R;                          // rows x 256
    u16* kv   = R + rmax * 256;             // rows x 1024 [k | v]
    u16* hid  = R;                          // rows x 2048 (Akv,kv dead by then)
    u16* aout = R + rmax * 2048;            // rows x 512  attn_out -> ffn

    GatherArgs ga{x, ts, W_temb, b_temb, eattr, ei};
    const dim3 blk(256);

    // ---- weight prep ----
    cvt_bf   <<<dim3(256),  blk, 0, stream>>>(W_node, wnq_cat, 262144);
    comb_w_bf<<<dim3(1024), blk, 0, stream>>>(Wq, W_node, wnq_cat + 262144, 512, 512);
    zero_u16 <<<dim3(1024), blk, 0, stream>>>(wkv_cat, 262144);
    comb_w_bf<<<dim3(256),  blk, 0, stream>>>(Wk, W_timef, wkv_cat, 128, 256);
    comb_w_bf<<<dim3(256),  blk, 0, stream>>>(Wv, W_edge, wkv_cat + 512 * 256 + 128, 128, 256);
    cvt_bf   <<<dim3(256),  blk, 0, stream>>>(Wo, wo,  262144);
    cvt_bf   <<<dim3(1024), blk, 0, stream>>>(W1, w1b, 1048576);
    cvt_bf   <<<dim3(1024), blk, 0, stream>>>(W2, w2b, 1048576);
    copy_f32 <<<dim3(2),    blk, 0, stream>>>(b_node, bias_nq, 512);
    comb_b   <<<dim3(2),    blk, 0, stream>>>(Wq, b_node,  bq, bias_nq + 512);
    comb_b   <<<dim3(2),    blk, 0, stream>>>(Wk, b_timef, bk, bias_kv);
    comb_b   <<<dim3(2),    blk, 0, stream>>>(Wv, b_edge,  bv, bias_kv + 512);

    for (int e0 = 0; e0 < LL; e0 += Ec) {
        int ec = LL - e0; if (ec > Ec) ec = Ec;
        const int rows = 4 * ec;
        const int gy = rows / 128;

        prep_kernel<<<dim3(rows), blk, 0, stream>>>(An, Akv, e0, ga);

        // [nodef|q] = An @ wnq_cat^T ; [k|v] = Akv @ wkv_cat^T
        gemm_mfma<false><<<dim3(8, gy), blk, 0, stream>>>(An,  wnq_cat, bias_nq, nodq, 1024, 512);
        gemm_mfma<false><<<dim3(8, gy), blk, 0, stream>>>(Akv, wkv_cat, bias_kv, kv,   1024, 256);

        attn_kernel<<<dim3(ec / 4), blk, 0, stream>>>(nodq, kv, An /*ctx*/);

        // attn_out = ctx @ Wo^T + bo ; out1 = LN(nodef + attn_out) -> An (bf16)
        gemm_mfma<false><<<dim3(4, gy), blk, 0, stream>>>(An, wo, bo, aout, 512, 512);
        ln1_kernel<<<dim3(rows), blk, 0, stream>>>(nodq, aout, g1, be1, An /*out1*/);

        // FFN: hid = gelu(out1 @ W1^T) ; ffn = hid @ W2^T -> aout
        gemm_mfma<true ><<<dim3(16, gy), blk, 0, stream>>>(An,  w1b, b1, hid, 2048, 512);
        gemm_mfma<false><<<dim3(4, gy),  blk, 0, stream>>>(hid, w2b, b2, aout /*ffn*/, 512, 2048);

        ln2_kernel<<<dim3(rows), blk, 0, stream>>>(An, aout, g2, be2, out, e0);
    }
}